// Round 6
// baseline (199.915 us; speedup 1.0000x reference)
//
#include <hip/hip_runtime.h>

typedef unsigned short u16;
typedef unsigned int u32;
typedef unsigned char u8;

#define HW 32768
#define NPX 65536
#define GEO_SIZE 8388608   /* 2*128*32768 elements */
#define EPS 1e-5f

// ---- workspace layout (byte offsets) ----
#define CNT_OFF  0         /* 128 u32 arrival counters (zeroed by stage1 each call) */
#define EAP_OFF  4096      /* f32 [4 grp][3 d][NPX] = 3145728 B */
#define T_OFF    8388608   /* bf16 t[o][px] = 128*65536*2 = 16777216 B */

#define LDS_STRIDE 136     /* u16 units: 128 + 8 pad */

typedef __bf16 bf16x8 __attribute__((ext_vector_type(8)));
typedef float f32x4 __attribute__((ext_vector_type(4)));
typedef float f32x2 __attribute__((ext_vector_type(2)));

__device__ __forceinline__ float bf2f(u16 u){ return __uint_as_float(((u32)u) << 16); }
__device__ __forceinline__ u16 f2bf(float f){
  u32 x = __float_as_uint(f);
  return (u16)((x + 0x7fffu + ((x >> 16) & 1u)) >> 16);
}
__device__ __forceinline__ float bflo(u32 w){ return __uint_as_float(w << 16); }
__device__ __forceinline__ float bfhi(u32 w){ return __uint_as_float(w & 0xffff0000u); }

__device__ __forceinline__ f32x2 pk_fma(f32x2 a, f32x2 b, f32x2 c){
  return __builtin_elementwise_fma(a, b, c);
}
__device__ __forceinline__ f32x2 pk_max(f32x2 a, f32x2 b){
  return __builtin_elementwise_max(a, b);
}

__device__ __forceinline__ float ldp(const void* p, int i, bool isbf){
  return isbf ? bf2f(((const u16*)p)[i]) : ((const float*)p)[i];
}

__device__ __forceinline__ bool sniff_bf16(const void* fv){
  const u16* w = (const u16*)fv;
  int hits = 0;
  for (int i = 0; i < 32; i++) {
    float v = bf2f(w[i]);
    hits += (v >= 0.45f && v <= 1.55f) ? 1 : 0;
  }
  return hits >= 26;
}

__device__ __forceinline__ int sniff_mask(const void* mask){
  const u8* mb = (const u8*)mask;
  int c01 = 0, ones = 0;
  for (int i = 0; i < 64; i++) { u8 v = mb[i]; c01 += (v <= 1); ones += (v == 1); }
  if (c01 == 64) return (ones >= 24) ? 0 : 1;
  const u16* mw = (const u16*)mask;
  int c3f = 0;
  for (int i = 0; i < 32; i++) c3f += (mw[i] == 0x3F80);
  return (c3f >= 22) ? 2 : 3;
}

__device__ __forceinline__ float mask_at(const void* m, int gi, int enc){
  if (enc == 0) return ((const u8*)m)[gi]  ? 1.f : 0.f;
  if (enc == 1) return ((const int*)m)[gi] ? 1.f : 0.f;
  if (enc == 2) return ((const u16*)m)[gi] ? 1.f : 0.f;
  return (((const float*)m)[gi] != 0.f) ? 1.f : 0.f;
}

// Stage 1 (self-contained): feat -> LDS transpose -> MFMA (raw fw as A) ->
// f32 epilogue applies BN scale/shift -> LDS -> coalesced t[o][px] bf16.
// Also zeroes the arrival counters for stage2 (block 0).
__global__ __launch_bounds__(256) void stage1_kernel(const void* __restrict__ feat,
                                                     const void* __restrict__ fw,
                                                     const void* __restrict__ fg,
                                                     const void* __restrict__ fb,
                                                     const void* __restrict__ fm,
                                                     const void* __restrict__ fv,
                                                     char* __restrict__ wsb){
  __shared__ u16 lds[128 * LDS_STRIDE];
  __shared__ float sfa[128], sha[128];
  u16* t = (u16*)(wsb + T_OFF);
  int tid = threadIdx.x;
  bool isbf = sniff_bf16(fv);
  if (blockIdx.x == 0 && tid < 128) ((u32*)(wsb + CNT_OFF))[tid] = 0;
  if (tid < 128) {
    float sf = ldp(fg, tid, isbf) * __frsqrt_rn(ldp(fv, tid, isbf) + EPS);
    sfa[tid] = sf;
    sha[tid] = ldp(fb, tid, isbf) - ldp(fm, tid, isbf) * sf;
  }
  int pxg = blockIdx.x * 128;
  int b = pxg >> 15, hw0 = pxg & 32767;

  // Phase A: stage feat tile into LDS, transposed to [px][c] packed bf16.
  {
    int cp = tid & 63, q = tid >> 6;
    int c0 = cp * 2;
    long e0 = (long)(b * 128 + c0) * HW + hw0 + q * 32;
    u16* base = lds + (q * 32) * LDS_STRIDE + c0;
    if (isbf) {
      const uint4* g0 = (const uint4*)((const u16*)feat + e0);
      const uint4* g1 = (const uint4*)((const u16*)feat + e0 + HW);
#pragma unroll
      for (int i = 0; i < 4; i++) {
        uint4 a = g0[i], c = g1[i];
        u32 av[4] = {a.x, a.y, a.z, a.w};
        u32 cv[4] = {c.x, c.y, c.z, c.w};
#pragma unroll
        for (int k = 0; k < 4; k++) {
          u32 lo = (av[k] & 0xffffu) | (cv[k] << 16);
          u32 hi = (av[k] >> 16) | (cv[k] & 0xffff0000u);
          *(u32*)(base + (i * 8 + k * 2 + 0) * LDS_STRIDE) = lo;
          *(u32*)(base + (i * 8 + k * 2 + 1) * LDS_STRIDE) = hi;
        }
      }
    } else {
      const float4* g0 = (const float4*)((const float*)feat + e0);
      const float4* g1 = (const float4*)((const float*)feat + e0 + HW);
#pragma unroll
      for (int i = 0; i < 8; i++) {
        float4 a = g0[i], c = g1[i];
        float av[4] = {a.x, a.y, a.z, a.w};
        float cv[4] = {c.x, c.y, c.z, c.w};
#pragma unroll
        for (int k = 0; k < 4; k++) {
          u32 v = (u32)f2bf(av[k]) | ((u32)f2bf(cv[k]) << 16);
          *(u32*)(base + (i * 4 + k) * LDS_STRIDE) = v;
        }
      }
    }
  }
  __syncthreads();

  // Phase B: MFMA. A = raw fw rows (L1-hot 32 KB), B = xT from LDS.
  int wave = tid >> 6, lane = tid & 63;
  int ln = lane & 15, quad = lane >> 4;
  int pxw = wave * 32;

  f32x4 acc[8][2];
#pragma unroll
  for (int ot = 0; ot < 8; ot++)
#pragma unroll
    for (int pt = 0; pt < 2; pt++) acc[ot][pt] = (f32x4){0.f, 0.f, 0.f, 0.f};

#pragma unroll
  for (int ks = 0; ks < 4; ks++) {
    bf16x8 a[8], bfr[2];
    if (isbf) {
      const uint4* Wq = (const uint4*)fw;
#pragma unroll
      for (int ot = 0; ot < 8; ot++)
        a[ot] = __builtin_bit_cast(bf16x8, Wq[(ot * 16 + ln) * 16 + ks * 4 + quad]);
    } else {
      const float* Wf = (const float*)fw;
#pragma unroll
      for (int ot = 0; ot < 8; ot++) {
        int base = (ot * 16 + ln) * 128 + ks * 32 + quad * 8;
        float4 lo = *(const float4*)(Wf + base);
        float4 hi = *(const float4*)(Wf + base + 4);
        uint4 p = make_uint4((u32)f2bf(lo.x) | ((u32)f2bf(lo.y) << 16),
                             (u32)f2bf(lo.z) | ((u32)f2bf(lo.w) << 16),
                             (u32)f2bf(hi.x) | ((u32)f2bf(hi.y) << 16),
                             (u32)f2bf(hi.z) | ((u32)f2bf(hi.w) << 16));
        a[ot] = __builtin_bit_cast(bf16x8, p);
      }
    }
#pragma unroll
    for (int pt = 0; pt < 2; pt++)
      bfr[pt] = __builtin_bit_cast(bf16x8,
          *(const uint4*)(lds + (pxw + pt * 16 + ln) * LDS_STRIDE + ks * 32 + quad * 8));
#pragma unroll
    for (int ot = 0; ot < 8; ot++)
#pragma unroll
      for (int pt = 0; pt < 2; pt++)
        acc[ot][pt] = __builtin_amdgcn_mfma_f32_16x16x32_bf16(a[ot], bfr[pt], acc[ot][pt], 0, 0, 0);
  }
  __syncthreads();

  // Epilogue: t = relu(sf*acc + shf), pack to LDS [o][px], store coalesced.
#pragma unroll
  for (int ot = 0; ot < 8; ot++) {
#pragma unroll
    for (int r = 0; r < 4; r++) {
      int o = ot * 16 + quad * 4 + r;
      float sf = sfa[o], sh = sha[o];
#pragma unroll
      for (int pt = 0; pt < 2; pt++) {
        float v = fmaxf(fmaf(acc[ot][pt][r], sf, sh), 0.f);
        lds[o * LDS_STRIDE + pxw + pt * 16 + ln] = f2bf(v);
      }
    }
  }
  __syncthreads();
  {
    int o = tid >> 1, half = tid & 1;
    const u16* src = lds + o * LDS_STRIDE + half * 64;
    uint4* dst = (uint4*)(t + o * NPX + pxg + half * 64);
#pragma unroll
    for (int k = 0; k < 8; k++) dst[k] = *(const uint4*)(src + k * 8);
  }
}

// Stage 2 + final: geo for one 32-ch group over a 512-px row; last-arriving
// group block per px-row does cart_out. Grid: 128 pxb x 4 grp = 512 blocks.
__global__ __launch_bounds__(256) void stage2_kernel(const void* __restrict__ cart,
                                                     const void* __restrict__ rawmask,
                                                     const void* __restrict__ pw,
                                                     const void* __restrict__ pg,
                                                     const void* __restrict__ pb,
                                                     const void* __restrict__ pm,
                                                     const void* __restrict__ pv,
                                                     const void* __restrict__ ew,
                                                     const void* __restrict__ eg,
                                                     const void* __restrict__ eb,
                                                     const void* __restrict__ em,
                                                     const void* __restrict__ ev,
                                                     const void* __restrict__ fv,
                                                     char* __restrict__ wsb,
                                                     void* __restrict__ out){
  __shared__ float sP[32][4];
  __shared__ float sE[32][3];
  __shared__ float sShe[3];
  __shared__ int s_last;
  u32* cnt = (u32*)(wsb + CNT_OFF);
  float* eap = (float*)(wsb + EAP_OFF);
  const u16* t = (const u16*)(wsb + T_OFF);

  int tid = threadIdx.x;
  int pxb = blockIdx.x & 127, grp = blockIdx.x >> 7;
  bool isbf = sniff_bf16(fv);
  int enc = sniff_mask(rawmask);

  if (tid < 32) {
    int o = grp * 32 + tid;
    float sp = ldp(pg, o, isbf) * __frsqrt_rn(ldp(pv, o, isbf) + EPS);
    sP[tid][0] = sp * ldp(pw, o * 3 + 0, isbf);
    sP[tid][1] = sp * ldp(pw, o * 3 + 1, isbf);
    sP[tid][2] = sp * ldp(pw, o * 3 + 2, isbf);
    sP[tid][3] = ldp(pb, o, isbf) - ldp(pm, o, isbf) * sp;
#pragma unroll
    for (int d = 0; d < 3; d++) {
      float se = ldp(eg, d, isbf) * __frsqrt_rn(ldp(ev, d, isbf) + EPS);
      sE[tid][d] = se * ldp(ew, d * 128 + o, isbf);
    }
  }
  if (tid < 3) {
    float se = ldp(eg, tid, isbf) * __frsqrt_rn(ldp(ev, tid, isbf) + EPS);
    sShe[tid] = ldp(eb, tid, isbf) - ldp(em, tid, isbf) * se;
  }
  __syncthreads();

  int px0 = pxb * 512 + tid * 2;            // even
  int b = px0 >> 15, hw = px0 & 32767;
  int h = hw >> 9, w = hw & 511;            // w even

  f32x2 rel2[9][3];
  f32x2 mv2[9];
  {
    float cr[12][3];
    float mm[12];
#pragma unroll
    for (int r = 0; r < 3; r++) {
#pragma unroll
      for (int c = 0; c < 4; c++) {
        int idx = r * 4 + c;
        int h2 = h + r - 1, w2 = w + c - 1;
        bool ok = ((unsigned)h2 < 64u) && ((unsigned)w2 < 512u);
        int hw2 = ok ? ((h2 << 9) | w2) : hw;
        int gi = b * HW + hw2;
        mm[idx] = ok ? mask_at(rawmask, gi, enc) : 0.f;
#pragma unroll
        for (int d = 0; d < 3; d++)
          cr[idx][d] = isbf ? bf2f(((const u16*)cart)[(b * 3 + d) * HW + hw2])
                            : ((const float*)cart)[(b * 3 + d) * HW + hw2];
      }
    }
#pragma unroll
    for (int r = 0; r < 3; r++)
#pragma unroll
      for (int cc = 0; cc < 3; cc++) {
        int n = r * 3 + cc;
        mv2[n] = (f32x2){mm[r * 4 + cc], mm[r * 4 + cc + 1]};
#pragma unroll
        for (int d = 0; d < 3; d++)
          rel2[n][d] = (f32x2){cr[r * 4 + cc][d] - cr[5][d],
                               cr[r * 4 + cc + 1][d] - cr[6][d]};
      }
  }

  f32x2 eA = {0.f, 0.f}, eB = {0.f, 0.f}, eC = {0.f, 0.f};
  u16* o16 = (u16*)out;
  float* of = (float*)out;
  const f32x2 zero2 = {0.f, 0.f};

#pragma unroll 4
  for (int j = 0; j < 32; j++) {
    int o = grp * 32 + j;
    const u16* tb = t + o * NPX + b * HW;
    u32 tw[3][3];
#pragma unroll
    for (int r = 0; r < 3; r++) {
      const u32* rp = (const u32*)(tb + (h + r - 1) * 512 + (w - 2));  // stays inside d_ws
      tw[r][0] = rp[0]; tw[r][1] = rp[1]; tw[r][2] = rp[2];
    }
    float Pxs = sP[j][0], Pys = sP[j][1], Pzs = sP[j][2], Pws = sP[j][3];
    f32x2 Px = {Pxs, Pxs}, Py = {Pys, Pys}, Pz = {Pzs, Pzs}, Pw = {Pws, Pws};
    f32x2 g = {0.f, 0.f};
#pragma unroll
    for (int r = 0; r < 3; r++) {
      float tm1 = bfhi(tw[r][0]);   // col w-1
      float t0  = bflo(tw[r][1]);   // col w
      float tp1 = bfhi(tw[r][1]);   // col w+1
      float tp2 = bflo(tw[r][2]);   // col w+2
      f32x2 tv[3] = {{tm1, t0}, {t0, tp1}, {tp1, tp2}};
#pragma unroll
      for (int cc = 0; cc < 3; cc++) {
        int n = r * 3 + cc;
        f32x2 pos = pk_max(pk_fma(Px, rel2[n][0],
                           pk_fma(Py, rel2[n][1],
                           pk_fma(Pz, rel2[n][2], Pw))), zero2);
        g = pk_max(g, (tv[cc] + pos) * mv2[n]);
      }
    }
    int gi = (b * 128 + o) * HW + hw;
    if (isbf) *(u32*)(o16 + gi) = (u32)f2bf(g.x) | ((u32)f2bf(g.y) << 16);
    else { of[gi] = g.x; of[gi + 1] = g.y; }
    f32x2 Ex = {sE[j][0], sE[j][0]}, Ey = {sE[j][1], sE[j][1]}, Ez = {sE[j][2], sE[j][2]};
    eA = pk_fma(Ex, g, eA);
    eB = pk_fma(Ey, g, eB);
    eC = pk_fma(Ez, g, eC);
  }
  *(f32x2*)(eap + (grp * 3 + 0) * NPX + px0) = eA;
  *(f32x2*)(eap + (grp * 3 + 1) * NPX + px0) = eB;
  *(f32x2*)(eap + (grp * 3 + 2) * NPX + px0) = eC;

  // Last-arrival reduction: 4 grp blocks per pxb; the last does cart_out.
  __syncthreads();
  if (tid == 0) {
    __threadfence();
    u32 old = __hip_atomic_fetch_add(&cnt[pxb], 1u, __ATOMIC_ACQ_REL,
                                     __HIP_MEMORY_SCOPE_AGENT);
    s_last = (old == 3u) ? 1 : 0;
  }
  __syncthreads();
  if (s_last) {
    __threadfence();   // acquire: other groups' eap stores now visible
    f32x2 s0 = {0.f, 0.f}, s1 = {0.f, 0.f}, s2 = {0.f, 0.f};
#pragma unroll
    for (int g = 0; g < 4; g++) {
      s0 += *(const f32x2*)(eap + (g * 3 + 0) * NPX + px0);
      s1 += *(const f32x2*)(eap + (g * 3 + 1) * NPX + px0);
      s2 += *(const f32x2*)(eap + (g * 3 + 2) * NPX + px0);
    }
    float m0 = mask_at(rawmask, b * HW + hw, enc);
    float m1 = mask_at(rawmask, b * HW + hw + 1, enc);
    float she0 = sShe[0], she1 = sShe[1], she2 = sShe[2];
    float c0a, c0b, c1a, c1b, c2a, c2b;
    if (isbf) {
      const u16* cb = (const u16*)cart + b * 3 * HW;
      c0a = bf2f(cb[hw]); c0b = bf2f(cb[hw + 1]);
      c1a = bf2f(cb[HW + hw]); c1b = bf2f(cb[HW + hw + 1]);
      c2a = bf2f(cb[2 * HW + hw]); c2b = bf2f(cb[2 * HW + hw + 1]);
    } else {
      const float* cb = (const float*)cart + b * 3 * HW;
      c0a = cb[hw]; c0b = cb[hw + 1];
      c1a = cb[HW + hw]; c1b = cb[HW + hw + 1];
      c2a = cb[2 * HW + hw]; c2b = cb[2 * HW + hw + 1];
    }
    float r0a = c0a + (s0.x + she0) * m0, r0b = c0b + (s0.y + she0) * m1;
    float r1a = c1a + (s1.x + she1) * m0, r1b = c1b + (s1.y + she1) * m1;
    float r2a = c2a + (s2.x + she2) * m0, r2b = c2b + (s2.y + she2) * m1;
    int cbase = GEO_SIZE + b * 3 * HW + hw;
    if (isbf) {
      *(u32*)(o16 + cbase)          = (u32)f2bf(r0a) | ((u32)f2bf(r0b) << 16);
      *(u32*)(o16 + cbase + HW)     = (u32)f2bf(r1a) | ((u32)f2bf(r1b) << 16);
      *(u32*)(o16 + cbase + 2 * HW) = (u32)f2bf(r2a) | ((u32)f2bf(r2b) << 16);
    } else {
      of[cbase] = r0a; of[cbase + 1] = r0b;
      of[cbase + HW] = r1a; of[cbase + HW + 1] = r1b;
      of[cbase + 2 * HW] = r2a; of[cbase + 2 * HW + 1] = r2b;
    }
  }
}

extern "C" void kernel_launch(void* const* d_in, const int* in_sizes, int n_in,
                              void* d_out, int out_size, void* d_ws, size_t ws_size,
                              hipStream_t stream) {
  const void* feat = d_in[0];
  const void* cart = d_in[1];
  const void* mask = d_in[2];
  char* wsb = (char*)d_ws;

  hipLaunchKernelGGL(stage1_kernel, dim3(512), dim3(256), 0, stream,
                     feat, d_in[8], d_in[9], d_in[10], d_in[11], d_in[12], wsb);
  hipLaunchKernelGGL(stage2_kernel, dim3(512), dim3(256), 0, stream,
                     cart, mask,
                     d_in[3], d_in[4], d_in[5], d_in[6], d_in[7],
                     d_in[13], d_in[14], d_in[15], d_in[16], d_in[17],
                     d_in[12], wsb, d_out);
}

// Round 7
// 188.159 us; speedup vs baseline: 1.0625x; 1.0625x over previous
//
#include <hip/hip_runtime.h>

typedef unsigned short u16;
typedef unsigned int u32;
typedef unsigned char u8;

#define HW 32768
#define NPX 65536
#define GEO_SIZE 8388608   /* 2*128*32768 elements */
#define EPS 1e-5f

// ---- workspace layout (byte offsets) ----
#define EAP_OFF  4096      /* f32 [8 grp][3 d][NPX] = 6291456 B */
#define T_OFF    8388608   /* bf16 t[o][px] = 128*65536*2 = 16777216 B */

#define LDS_STRIDE 136     /* u16 units: 128 + 8 pad */

typedef __bf16 bf16x8 __attribute__((ext_vector_type(8)));
typedef float f32x4 __attribute__((ext_vector_type(4)));
typedef float f32x2 __attribute__((ext_vector_type(2)));

__device__ __forceinline__ float bf2f(u16 u){ return __uint_as_float(((u32)u) << 16); }
__device__ __forceinline__ u16 f2bf(float f){
  u32 x = __float_as_uint(f);
  return (u16)((x + 0x7fffu + ((x >> 16) & 1u)) >> 16);
}
__device__ __forceinline__ float bflo(u32 w){ return __uint_as_float(w << 16); }
__device__ __forceinline__ float bfhi(u32 w){ return __uint_as_float(w & 0xffff0000u); }

__device__ __forceinline__ f32x2 pk_fma(f32x2 a, f32x2 b, f32x2 c){
  return __builtin_elementwise_fma(a, b, c);
}
__device__ __forceinline__ f32x2 pk_max(f32x2 a, f32x2 b){
  return __builtin_elementwise_max(a, b);
}

__device__ __forceinline__ float ldp(const void* p, int i, bool isbf){
  return isbf ? bf2f(((const u16*)p)[i]) : ((const float*)p)[i];
}

__device__ __forceinline__ bool sniff_bf16(const void* fv){
  const u16* w = (const u16*)fv;
  int hits = 0;
  for (int i = 0; i < 32; i++) {
    float v = bf2f(w[i]);
    hits += (v >= 0.45f && v <= 1.55f) ? 1 : 0;
  }
  return hits >= 26;
}

__device__ __forceinline__ int sniff_mask(const void* mask){
  const u8* mb = (const u8*)mask;
  int c01 = 0, ones = 0;
  for (int i = 0; i < 64; i++) { u8 v = mb[i]; c01 += (v <= 1); ones += (v == 1); }
  if (c01 == 64) return (ones >= 24) ? 0 : 1;
  const u16* mw = (const u16*)mask;
  int c3f = 0;
  for (int i = 0; i < 32; i++) c3f += (mw[i] == 0x3F80);
  return (c3f >= 22) ? 2 : 3;
}

__device__ __forceinline__ float mask_at(const void* m, int gi, int enc){
  if (enc == 0) return ((const u8*)m)[gi]  ? 1.f : 0.f;
  if (enc == 1) return ((const int*)m)[gi] ? 1.f : 0.f;
  if (enc == 2) return ((const u16*)m)[gi] ? 1.f : 0.f;
  return (((const float*)m)[gi] != 0.f) ? 1.f : 0.f;
}

// Stage 1 (self-contained): feat -> LDS transpose -> MFMA (raw fw as A) ->
// f32 epilogue applies BN scale/shift -> LDS -> coalesced t[o][px] bf16.
__global__ __launch_bounds__(256) void stage1_kernel(const void* __restrict__ feat,
                                                     const void* __restrict__ fw,
                                                     const void* __restrict__ fg,
                                                     const void* __restrict__ fb,
                                                     const void* __restrict__ fm,
                                                     const void* __restrict__ fv,
                                                     char* __restrict__ wsb){
  __shared__ u16 lds[128 * LDS_STRIDE];
  __shared__ float sfa[128], sha[128];
  u16* t = (u16*)(wsb + T_OFF);
  int tid = threadIdx.x;
  bool isbf = sniff_bf16(fv);
  if (tid < 128) {
    float sf = ldp(fg, tid, isbf) * __frsqrt_rn(ldp(fv, tid, isbf) + EPS);
    sfa[tid] = sf;
    sha[tid] = ldp(fb, tid, isbf) - ldp(fm, tid, isbf) * sf;
  }
  int pxg = blockIdx.x * 128;
  int b = pxg >> 15, hw0 = pxg & 32767;

  // Phase A: stage feat tile into LDS, transposed to [px][c] packed bf16.
  {
    int cp = tid & 63, q = tid >> 6;
    int c0 = cp * 2;
    long e0 = (long)(b * 128 + c0) * HW + hw0 + q * 32;
    u16* base = lds + (q * 32) * LDS_STRIDE + c0;
    if (isbf) {
      const uint4* g0 = (const uint4*)((const u16*)feat + e0);
      const uint4* g1 = (const uint4*)((const u16*)feat + e0 + HW);
#pragma unroll
      for (int i = 0; i < 4; i++) {
        uint4 a = g0[i], c = g1[i];
        u32 av[4] = {a.x, a.y, a.z, a.w};
        u32 cv[4] = {c.x, c.y, c.z, c.w};
#pragma unroll
        for (int k = 0; k < 4; k++) {
          u32 lo = (av[k] & 0xffffu) | (cv[k] << 16);
          u32 hi = (av[k] >> 16) | (cv[k] & 0xffff0000u);
          *(u32*)(base + (i * 8 + k * 2 + 0) * LDS_STRIDE) = lo;
          *(u32*)(base + (i * 8 + k * 2 + 1) * LDS_STRIDE) = hi;
        }
      }
    } else {
      const float4* g0 = (const float4*)((const float*)feat + e0);
      const float4* g1 = (const float4*)((const float*)feat + e0 + HW);
#pragma unroll
      for (int i = 0; i < 8; i++) {
        float4 a = g0[i], c = g1[i];
        float av[4] = {a.x, a.y, a.z, a.w};
        float cv[4] = {c.x, c.y, c.z, c.w};
#pragma unroll
        for (int k = 0; k < 4; k++) {
          u32 v = (u32)f2bf(av[k]) | ((u32)f2bf(cv[k]) << 16);
          *(u32*)(base + (i * 4 + k) * LDS_STRIDE) = v;
        }
      }
    }
  }
  __syncthreads();

  // Phase B: MFMA. A = raw fw rows (L1-hot 32 KB), B = xT from LDS.
  int wave = tid >> 6, lane = tid & 63;
  int ln = lane & 15, quad = lane >> 4;
  int pxw = wave * 32;

  f32x4 acc[8][2];
#pragma unroll
  for (int ot = 0; ot < 8; ot++)
#pragma unroll
    for (int pt = 0; pt < 2; pt++) acc[ot][pt] = (f32x4){0.f, 0.f, 0.f, 0.f};

#pragma unroll
  for (int ks = 0; ks < 4; ks++) {
    bf16x8 a[8], bfr[2];
    if (isbf) {
      const uint4* Wq = (const uint4*)fw;
#pragma unroll
      for (int ot = 0; ot < 8; ot++)
        a[ot] = __builtin_bit_cast(bf16x8, Wq[(ot * 16 + ln) * 16 + ks * 4 + quad]);
    } else {
      const float* Wf = (const float*)fw;
#pragma unroll
      for (int ot = 0; ot < 8; ot++) {
        int base = (ot * 16 + ln) * 128 + ks * 32 + quad * 8;
        float4 lo = *(const float4*)(Wf + base);
        float4 hi = *(const float4*)(Wf + base + 4);
        uint4 p = make_uint4((u32)f2bf(lo.x) | ((u32)f2bf(lo.y) << 16),
                             (u32)f2bf(lo.z) | ((u32)f2bf(lo.w) << 16),
                             (u32)f2bf(hi.x) | ((u32)f2bf(hi.y) << 16),
                             (u32)f2bf(hi.z) | ((u32)f2bf(hi.w) << 16));
        a[ot] = __builtin_bit_cast(bf16x8, p);
      }
    }
#pragma unroll
    for (int pt = 0; pt < 2; pt++)
      bfr[pt] = __builtin_bit_cast(bf16x8,
          *(const uint4*)(lds + (pxw + pt * 16 + ln) * LDS_STRIDE + ks * 32 + quad * 8));
#pragma unroll
    for (int ot = 0; ot < 8; ot++)
#pragma unroll
      for (int pt = 0; pt < 2; pt++)
        acc[ot][pt] = __builtin_amdgcn_mfma_f32_16x16x32_bf16(a[ot], bfr[pt], acc[ot][pt], 0, 0, 0);
  }
  __syncthreads();

  // Epilogue: t = relu(sf*acc + shf), pack to LDS [o][px], store coalesced.
#pragma unroll
  for (int ot = 0; ot < 8; ot++) {
#pragma unroll
    for (int r = 0; r < 4; r++) {
      int o = ot * 16 + quad * 4 + r;
      float sf = sfa[o], sh = sha[o];
#pragma unroll
      for (int pt = 0; pt < 2; pt++) {
        float v = fmaxf(fmaf(acc[ot][pt][r], sf, sh), 0.f);
        lds[o * LDS_STRIDE + pxw + pt * 16 + ln] = f2bf(v);
      }
    }
  }
  __syncthreads();
  {
    int o = tid >> 1, half = tid & 1;
    const u16* src = lds + o * LDS_STRIDE + half * 64;
    uint4* dst = (uint4*)(t + o * NPX + pxg + half * 64);
#pragma unroll
    for (int k = 0; k < 8; k++) dst[k] = *(const uint4*)(src + k * 8);
  }
}

// Stage 2: geo for one 16-ch group over a 512-px row + per-group ea partials.
// Grid: 128 pxb x 8 grp = 1024 blocks (16 waves/CU for latency hiding).
__global__ __launch_bounds__(256) void stage2_kernel(const void* __restrict__ cart,
                                                     const void* __restrict__ rawmask,
                                                     const void* __restrict__ pw,
                                                     const void* __restrict__ pg,
                                                     const void* __restrict__ pb,
                                                     const void* __restrict__ pm,
                                                     const void* __restrict__ pv,
                                                     const void* __restrict__ ew,
                                                     const void* __restrict__ eg,
                                                     const void* __restrict__ eb,
                                                     const void* __restrict__ em,
                                                     const void* __restrict__ ev,
                                                     const void* __restrict__ fv,
                                                     char* __restrict__ wsb,
                                                     void* __restrict__ out){
  __shared__ float sP[16][4];
  __shared__ float sE[16][3];
  float* eap = (float*)(wsb + EAP_OFF);
  const u16* t = (const u16*)(wsb + T_OFF);

  int tid = threadIdx.x;
  int pxb = blockIdx.x & 127, grp = blockIdx.x >> 7;
  bool isbf = sniff_bf16(fv);
  int enc = sniff_mask(rawmask);

  if (tid < 16) {
    int o = grp * 16 + tid;
    float sp = ldp(pg, o, isbf) * __frsqrt_rn(ldp(pv, o, isbf) + EPS);
    sP[tid][0] = sp * ldp(pw, o * 3 + 0, isbf);
    sP[tid][1] = sp * ldp(pw, o * 3 + 1, isbf);
    sP[tid][2] = sp * ldp(pw, o * 3 + 2, isbf);
    sP[tid][3] = ldp(pb, o, isbf) - ldp(pm, o, isbf) * sp;
#pragma unroll
    for (int d = 0; d < 3; d++) {
      float se = ldp(eg, d, isbf) * __frsqrt_rn(ldp(ev, d, isbf) + EPS);
      sE[tid][d] = se * ldp(ew, d * 128 + o, isbf);
    }
  }
  __syncthreads();

  int px0 = pxb * 512 + tid * 2;            // even
  int b = px0 >> 15, hw = px0 & 32767;
  int h = hw >> 9, w = hw & 511;            // w even

  f32x2 rel2[9][3];
  f32x2 mv2[9];
  {
    float cr[12][3];
    float mm[12];
#pragma unroll
    for (int r = 0; r < 3; r++) {
#pragma unroll
      for (int c = 0; c < 4; c++) {
        int idx = r * 4 + c;
        int h2 = h + r - 1, w2 = w + c - 1;
        bool ok = ((unsigned)h2 < 64u) && ((unsigned)w2 < 512u);
        int hw2 = ok ? ((h2 << 9) | w2) : hw;
        int gi = b * HW + hw2;
        mm[idx] = ok ? mask_at(rawmask, gi, enc) : 0.f;
#pragma unroll
        for (int d = 0; d < 3; d++)
          cr[idx][d] = isbf ? bf2f(((const u16*)cart)[(b * 3 + d) * HW + hw2])
                            : ((const float*)cart)[(b * 3 + d) * HW + hw2];
      }
    }
#pragma unroll
    for (int r = 0; r < 3; r++)
#pragma unroll
      for (int cc = 0; cc < 3; cc++) {
        int n = r * 3 + cc;
        mv2[n] = (f32x2){mm[r * 4 + cc], mm[r * 4 + cc + 1]};
#pragma unroll
        for (int d = 0; d < 3; d++)
          rel2[n][d] = (f32x2){cr[r * 4 + cc][d] - cr[5][d],
                               cr[r * 4 + cc + 1][d] - cr[6][d]};
      }
  }

  f32x2 eA = {0.f, 0.f}, eB = {0.f, 0.f}, eC = {0.f, 0.f};
  u16* o16 = (u16*)out;
  float* of = (float*)out;
  const f32x2 zero2 = {0.f, 0.f};

#pragma unroll 4
  for (int j = 0; j < 16; j++) {
    int o = grp * 16 + j;
    const u16* tb = t + o * NPX + b * HW;
    u32 tw[3][3];
#pragma unroll
    for (int r = 0; r < 3; r++) {
      const u32* rp = (const u32*)(tb + (h + r - 1) * 512 + (w - 2));  // stays inside d_ws
      tw[r][0] = rp[0]; tw[r][1] = rp[1]; tw[r][2] = rp[2];
    }
    float Pxs = sP[j][0], Pys = sP[j][1], Pzs = sP[j][2], Pws = sP[j][3];
    f32x2 Px = {Pxs, Pxs}, Py = {Pys, Pys}, Pz = {Pzs, Pzs}, Pw = {Pws, Pws};
    f32x2 g = {0.f, 0.f};
#pragma unroll
    for (int r = 0; r < 3; r++) {
      float tm1 = bfhi(tw[r][0]);   // col w-1
      float t0  = bflo(tw[r][1]);   // col w
      float tp1 = bfhi(tw[r][1]);   // col w+1
      float tp2 = bflo(tw[r][2]);   // col w+2
      f32x2 tv[3] = {{tm1, t0}, {t0, tp1}, {tp1, tp2}};
#pragma unroll
      for (int cc = 0; cc < 3; cc++) {
        int n = r * 3 + cc;
        f32x2 pos = pk_max(pk_fma(Px, rel2[n][0],
                           pk_fma(Py, rel2[n][1],
                           pk_fma(Pz, rel2[n][2], Pw))), zero2);
        g = pk_max(g, (tv[cc] + pos) * mv2[n]);
      }
    }
    int gi = (b * 128 + o) * HW + hw;
    if (isbf) *(u32*)(o16 + gi) = (u32)f2bf(g.x) | ((u32)f2bf(g.y) << 16);
    else { of[gi] = g.x; of[gi + 1] = g.y; }
    f32x2 Ex = {sE[j][0], sE[j][0]}, Ey = {sE[j][1], sE[j][1]}, Ez = {sE[j][2], sE[j][2]};
    eA = pk_fma(Ex, g, eA);
    eB = pk_fma(Ey, g, eB);
    eC = pk_fma(Ez, g, eC);
  }
  *(f32x2*)(eap + (grp * 3 + 0) * NPX + px0) = eA;
  *(f32x2*)(eap + (grp * 3 + 1) * NPX + px0) = eB;
  *(f32x2*)(eap + (grp * 3 + 2) * NPX + px0) = eC;
}

// Final: sum 8 group partials, cart_out. 2 px/thread, grid 128.
__global__ __launch_bounds__(256) void final_kernel(const void* __restrict__ cart,
                                                    const void* __restrict__ rawmask,
                                                    const void* __restrict__ eg,
                                                    const void* __restrict__ eb,
                                                    const void* __restrict__ em,
                                                    const void* __restrict__ ev,
                                                    const void* __restrict__ fv,
                                                    const char* __restrict__ wsb,
                                                    void* __restrict__ out){
  const float* eap = (const float*)(wsb + EAP_OFF);
  bool isbf = sniff_bf16(fv);
  int enc = sniff_mask(rawmask);
  int px0 = (blockIdx.x * 256 + threadIdx.x) * 2;
  int b = px0 >> 15, hw = px0 & 32767;
  f32x2 s0 = {0.f, 0.f}, s1 = {0.f, 0.f}, s2 = {0.f, 0.f};
#pragma unroll
  for (int g = 0; g < 8; g++) {
    s0 += *(const f32x2*)(eap + (g * 3 + 0) * NPX + px0);
    s1 += *(const f32x2*)(eap + (g * 3 + 1) * NPX + px0);
    s2 += *(const f32x2*)(eap + (g * 3 + 2) * NPX + px0);
  }
  float she[3];
#pragma unroll
  for (int d = 0; d < 3; d++) {
    float se = ldp(eg, d, isbf) * __frsqrt_rn(ldp(ev, d, isbf) + EPS);
    she[d] = ldp(eb, d, isbf) - ldp(em, d, isbf) * se;
  }
  float m0 = mask_at(rawmask, b * HW + hw, enc);
  float m1 = mask_at(rawmask, b * HW + hw + 1, enc);
  float c0a, c0b, c1a, c1b, c2a, c2b;
  if (isbf) {
    const u16* cb = (const u16*)cart + b * 3 * HW;
    c0a = bf2f(cb[hw]); c0b = bf2f(cb[hw + 1]);
    c1a = bf2f(cb[HW + hw]); c1b = bf2f(cb[HW + hw + 1]);
    c2a = bf2f(cb[2 * HW + hw]); c2b = bf2f(cb[2 * HW + hw + 1]);
  } else {
    const float* cb = (const float*)cart + b * 3 * HW;
    c0a = cb[hw]; c0b = cb[hw + 1];
    c1a = cb[HW + hw]; c1b = cb[HW + hw + 1];
    c2a = cb[2 * HW + hw]; c2b = cb[2 * HW + hw + 1];
  }
  float r0a = c0a + (s0.x + she[0]) * m0, r0b = c0b + (s0.y + she[0]) * m1;
  float r1a = c1a + (s1.x + she[1]) * m0, r1b = c1b + (s1.y + she[1]) * m1;
  float r2a = c2a + (s2.x + she[2]) * m0, r2b = c2b + (s2.y + she[2]) * m1;
  int cbase = GEO_SIZE + b * 3 * HW + hw;
  if (isbf) {
    u16* o16 = (u16*)out;
    *(u32*)(o16 + cbase)          = (u32)f2bf(r0a) | ((u32)f2bf(r0b) << 16);
    *(u32*)(o16 + cbase + HW)     = (u32)f2bf(r1a) | ((u32)f2bf(r1b) << 16);
    *(u32*)(o16 + cbase + 2 * HW) = (u32)f2bf(r2a) | ((u32)f2bf(r2b) << 16);
  } else {
    float* of = (float*)out;
    of[cbase] = r0a; of[cbase + 1] = r0b;
    of[cbase + HW] = r1a; of[cbase + HW + 1] = r1b;
    of[cbase + 2 * HW] = r2a; of[cbase + 2 * HW + 1] = r2b;
  }
}

extern "C" void kernel_launch(void* const* d_in, const int* in_sizes, int n_in,
                              void* d_out, int out_size, void* d_ws, size_t ws_size,
                              hipStream_t stream) {
  const void* feat = d_in[0];
  const void* cart = d_in[1];
  const void* mask = d_in[2];
  char* wsb = (char*)d_ws;

  hipLaunchKernelGGL(stage1_kernel, dim3(512), dim3(256), 0, stream,
                     feat, d_in[8], d_in[9], d_in[10], d_in[11], d_in[12], wsb);
  hipLaunchKernelGGL(stage2_kernel, dim3(1024), dim3(256), 0, stream,
                     cart, mask,
                     d_in[3], d_in[4], d_in[5], d_in[6], d_in[7],
                     d_in[13], d_in[14], d_in[15], d_in[16], d_in[17],
                     d_in[12], wsb, d_out);
  hipLaunchKernelGGL(final_kernel, dim3(128), dim3(256), 0, stream,
                     cart, mask, d_in[14], d_in[15], d_in[16], d_in[17],
                     d_in[12], wsb, d_out);
}

// Round 8
// 185.381 us; speedup vs baseline: 1.0784x; 1.0150x over previous
//
#include <hip/hip_runtime.h>

typedef unsigned short u16;
typedef unsigned int u32;
typedef unsigned char u8;

#define HW 32768
#define NPX 65536
#define GEO_SIZE 8388608   /* 2*128*32768 elements */
#define EPS 1e-5f

// ---- workspace layout (byte offsets) ----
#define EAP_OFF  4096      /* f32 [8 grp][3 d][NPX] = 6291456 B */
#define T_OFF    8388608   /* bf16 t[o][px] = 128*65536*2 = 16777216 B */

#define LDS_STRIDE 136     /* u16 units: 128 + 8 pad (stage1) */

typedef __bf16 bf16x8 __attribute__((ext_vector_type(8)));
typedef float f32x4 __attribute__((ext_vector_type(4)));
typedef float f32x2 __attribute__((ext_vector_type(2)));

__device__ __forceinline__ float bf2f(u16 u){ return __uint_as_float(((u32)u) << 16); }
__device__ __forceinline__ u16 f2bf(float f){
  u32 x = __float_as_uint(f);
  return (u16)((x + 0x7fffu + ((x >> 16) & 1u)) >> 16);
}
__device__ __forceinline__ float bflo(u32 w){ return __uint_as_float(w << 16); }
__device__ __forceinline__ float bfhi(u32 w){ return __uint_as_float(w & 0xffff0000u); }

__device__ __forceinline__ f32x2 pk_fma(f32x2 a, f32x2 b, f32x2 c){
  return __builtin_elementwise_fma(a, b, c);
}
__device__ __forceinline__ f32x2 pk_max(f32x2 a, f32x2 b){
  return __builtin_elementwise_max(a, b);
}

__device__ __forceinline__ float ldp(const void* p, int i, bool isbf){
  return isbf ? bf2f(((const u16*)p)[i]) : ((const float*)p)[i];
}

__device__ __forceinline__ bool sniff_bf16(const void* fv){
  const u16* w = (const u16*)fv;
  int hits = 0;
  for (int i = 0; i < 32; i++) {
    float v = bf2f(w[i]);
    hits += (v >= 0.45f && v <= 1.55f) ? 1 : 0;
  }
  return hits >= 26;
}

__device__ __forceinline__ int sniff_mask(const void* mask){
  const u8* mb = (const u8*)mask;
  int c01 = 0, ones = 0;
  for (int i = 0; i < 64; i++) { u8 v = mb[i]; c01 += (v <= 1); ones += (v == 1); }
  if (c01 == 64) return (ones >= 24) ? 0 : 1;
  const u16* mw = (const u16*)mask;
  int c3f = 0;
  for (int i = 0; i < 32; i++) c3f += (mw[i] == 0x3F80);
  return (c3f >= 22) ? 2 : 3;
}

__device__ __forceinline__ float mask_at(const void* m, int gi, int enc){
  if (enc == 0) return ((const u8*)m)[gi]  ? 1.f : 0.f;
  if (enc == 1) return ((const int*)m)[gi] ? 1.f : 0.f;
  if (enc == 2) return ((const u16*)m)[gi] ? 1.f : 0.f;
  return (((const float*)m)[gi] != 0.f) ? 1.f : 0.f;
}

// Stage 1 (self-contained): feat -> LDS transpose -> MFMA (raw fw as A) ->
// f32 epilogue applies BN scale/shift -> LDS -> coalesced t[o][px] bf16.
__global__ __launch_bounds__(256) void stage1_kernel(const void* __restrict__ feat,
                                                     const void* __restrict__ fw,
                                                     const void* __restrict__ fg,
                                                     const void* __restrict__ fb,
                                                     const void* __restrict__ fm,
                                                     const void* __restrict__ fv,
                                                     char* __restrict__ wsb){
  __shared__ u16 lds[128 * LDS_STRIDE];
  __shared__ float sfa[128], sha[128];
  u16* t = (u16*)(wsb + T_OFF);
  int tid = threadIdx.x;
  bool isbf = sniff_bf16(fv);
  if (tid < 128) {
    float sf = ldp(fg, tid, isbf) * __frsqrt_rn(ldp(fv, tid, isbf) + EPS);
    sfa[tid] = sf;
    sha[tid] = ldp(fb, tid, isbf) - ldp(fm, tid, isbf) * sf;
  }
  int pxg = blockIdx.x * 128;
  int b = pxg >> 15, hw0 = pxg & 32767;

  // Phase A: stage feat tile into LDS, transposed to [px][c] packed bf16.
  {
    int cp = tid & 63, q = tid >> 6;
    int c0 = cp * 2;
    long e0 = (long)(b * 128 + c0) * HW + hw0 + q * 32;
    u16* base = lds + (q * 32) * LDS_STRIDE + c0;
    if (isbf) {
      const uint4* g0 = (const uint4*)((const u16*)feat + e0);
      const uint4* g1 = (const uint4*)((const u16*)feat + e0 + HW);
#pragma unroll
      for (int i = 0; i < 4; i++) {
        uint4 a = g0[i], c = g1[i];
        u32 av[4] = {a.x, a.y, a.z, a.w};
        u32 cv[4] = {c.x, c.y, c.z, c.w};
#pragma unroll
        for (int k = 0; k < 4; k++) {
          u32 lo = (av[k] & 0xffffu) | (cv[k] << 16);
          u32 hi = (av[k] >> 16) | (cv[k] & 0xffff0000u);
          *(u32*)(base + (i * 8 + k * 2 + 0) * LDS_STRIDE) = lo;
          *(u32*)(base + (i * 8 + k * 2 + 1) * LDS_STRIDE) = hi;
        }
      }
    } else {
      const float4* g0 = (const float4*)((const float*)feat + e0);
      const float4* g1 = (const float4*)((const float*)feat + e0 + HW);
#pragma unroll
      for (int i = 0; i < 8; i++) {
        float4 a = g0[i], c = g1[i];
        float av[4] = {a.x, a.y, a.z, a.w};
        float cv[4] = {c.x, c.y, c.z, c.w};
#pragma unroll
        for (int k = 0; k < 4; k++) {
          u32 v = (u32)f2bf(av[k]) | ((u32)f2bf(cv[k]) << 16);
          *(u32*)(base + (i * 4 + k) * LDS_STRIDE) = v;
        }
      }
    }
  }
  __syncthreads();

  // Phase B: MFMA. A = raw fw rows (L1-hot 32 KB), B = xT from LDS.
  int wave = tid >> 6, lane = tid & 63;
  int ln = lane & 15, quad = lane >> 4;
  int pxw = wave * 32;

  f32x4 acc[8][2];
#pragma unroll
  for (int ot = 0; ot < 8; ot++)
#pragma unroll
    for (int pt = 0; pt < 2; pt++) acc[ot][pt] = (f32x4){0.f, 0.f, 0.f, 0.f};

#pragma unroll
  for (int ks = 0; ks < 4; ks++) {
    bf16x8 a[8], bfr[2];
    if (isbf) {
      const uint4* Wq = (const uint4*)fw;
#pragma unroll
      for (int ot = 0; ot < 8; ot++)
        a[ot] = __builtin_bit_cast(bf16x8, Wq[(ot * 16 + ln) * 16 + ks * 4 + quad]);
    } else {
      const float* Wf = (const float*)fw;
#pragma unroll
      for (int ot = 0; ot < 8; ot++) {
        int base = (ot * 16 + ln) * 128 + ks * 32 + quad * 8;
        float4 lo = *(const float4*)(Wf + base);
        float4 hi = *(const float4*)(Wf + base + 4);
        uint4 p = make_uint4((u32)f2bf(lo.x) | ((u32)f2bf(lo.y) << 16),
                             (u32)f2bf(lo.z) | ((u32)f2bf(lo.w) << 16),
                             (u32)f2bf(hi.x) | ((u32)f2bf(hi.y) << 16),
                             (u32)f2bf(hi.z) | ((u32)f2bf(hi.w) << 16));
        a[ot] = __builtin_bit_cast(bf16x8, p);
      }
    }
#pragma unroll
    for (int pt = 0; pt < 2; pt++)
      bfr[pt] = __builtin_bit_cast(bf16x8,
          *(const uint4*)(lds + (pxw + pt * 16 + ln) * LDS_STRIDE + ks * 32 + quad * 8));
#pragma unroll
    for (int ot = 0; ot < 8; ot++)
#pragma unroll
      for (int pt = 0; pt < 2; pt++)
        acc[ot][pt] = __builtin_amdgcn_mfma_f32_16x16x32_bf16(a[ot], bfr[pt], acc[ot][pt], 0, 0, 0);
  }
  __syncthreads();

  // Epilogue: t = relu(sf*acc + shf), pack to LDS [o][px], store coalesced.
#pragma unroll
  for (int ot = 0; ot < 8; ot++) {
#pragma unroll
    for (int r = 0; r < 4; r++) {
      int o = ot * 16 + quad * 4 + r;
      float sf = sfa[o], sh = sha[o];
#pragma unroll
      for (int pt = 0; pt < 2; pt++) {
        float v = fmaxf(fmaf(acc[ot][pt][r], sf, sh), 0.f);
        lds[o * LDS_STRIDE + pxw + pt * 16 + ln] = f2bf(v);
      }
    }
  }
  __syncthreads();
  {
    int o = tid >> 1, half = tid & 1;
    const u16* src = lds + o * LDS_STRIDE + half * 64;
    uint4* dst = (uint4*)(t + o * NPX + pxg + half * 64);
#pragma unroll
    for (int k = 0; k < 8; k++) dst[k] = *(const uint4*)(src + k * 8);
  }
}

// Stage 2: one 512-px row x 16-ch group per block; t-tile staged in LDS.
// Grid: 128 px-rows x 8 grp = 1024 blocks. LDS 48KB -> 3 blocks/CU.
__global__ __launch_bounds__(256) void stage2_kernel(const void* __restrict__ cart,
                                                     const void* __restrict__ rawmask,
                                                     const void* __restrict__ pw,
                                                     const void* __restrict__ pg,
                                                     const void* __restrict__ pb,
                                                     const void* __restrict__ pm,
                                                     const void* __restrict__ pv,
                                                     const void* __restrict__ ew,
                                                     const void* __restrict__ eg,
                                                     const void* __restrict__ eb,
                                                     const void* __restrict__ em,
                                                     const void* __restrict__ ev,
                                                     const void* __restrict__ fv,
                                                     char* __restrict__ wsb,
                                                     void* __restrict__ out){
  __shared__ u16 ltile[48 * 512];    // [16 ch][3 rows][512 w] = 48 KB, no pad needed
  __shared__ float sP[16][4];
  __shared__ float sE[16][3];
  float* eap = (float*)(wsb + EAP_OFF);
  const u16* t = (const u16*)(wsb + T_OFF);

  int tid = threadIdx.x;
  int pxb = blockIdx.x & 127, grp = blockIdx.x >> 7;
  int b = pxb >> 6, h = pxb & 63;
  bool isbf = sniff_bf16(fv);
  int enc = sniff_mask(rawmask);

  if (tid < 16) {
    int o = grp * 16 + tid;
    float sp = ldp(pg, o, isbf) * __frsqrt_rn(ldp(pv, o, isbf) + EPS);
    sP[tid][0] = sp * ldp(pw, o * 3 + 0, isbf);
    sP[tid][1] = sp * ldp(pw, o * 3 + 1, isbf);
    sP[tid][2] = sp * ldp(pw, o * 3 + 2, isbf);
    sP[tid][3] = ldp(pb, o, isbf) - ldp(pm, o, isbf) * sp;
#pragma unroll
    for (int d = 0; d < 3; d++) {
      float se = ldp(eg, d, isbf) * __frsqrt_rn(ldp(ev, d, isbf) + EPS);
      sE[tid][d] = se * ldp(ew, d * 128 + o, isbf);
    }
  }

  // Cooperative stage of t rows h-1..h+1 (clamped) for 16 channels into LDS.
  {
    int ck = tid & 63, r0 = tid >> 6;         // 64 dwordx4-chunks per row, 4 rows in flight
#pragma unroll
    for (int rr = r0; rr < 48; rr += 4) {
      int j = rr / 3, r = rr - 3 * j;
      int hc = min(max(h + r - 1, 0), 63);    // clamped row (values masked at edges)
      const uint4* src = (const uint4*)(t + (grp * 16 + j) * NPX + b * HW + hc * 512 + ck * 8);
      *(uint4*)((char*)ltile + rr * 1024 + ck * 16) = *src;
    }
  }
  __syncthreads();

  int px0 = pxb * 512 + tid * 2;            // even
  int hw = px0 & 32767;
  int w = hw & 511;                          // w even

  f32x2 rel2[9][3];
  f32x2 mv2[9];
  {
    float cr[12][3];
    float mm[12];
#pragma unroll
    for (int r = 0; r < 3; r++) {
#pragma unroll
      for (int c = 0; c < 4; c++) {
        int idx = r * 4 + c;
        int h2 = h + r - 1, w2 = w + c - 1;
        bool ok = ((unsigned)h2 < 64u) && ((unsigned)w2 < 512u);
        int hw2 = ok ? ((h2 << 9) | w2) : hw;
        int gi = b * HW + hw2;
        mm[idx] = ok ? mask_at(rawmask, gi, enc) : 0.f;
#pragma unroll
        for (int d = 0; d < 3; d++)
          cr[idx][d] = isbf ? bf2f(((const u16*)cart)[(b * 3 + d) * HW + hw2])
                            : ((const float*)cart)[(b * 3 + d) * HW + hw2];
      }
    }
#pragma unroll
    for (int r = 0; r < 3; r++)
#pragma unroll
      for (int cc = 0; cc < 3; cc++) {
        int n = r * 3 + cc;
        mv2[n] = (f32x2){mm[r * 4 + cc], mm[r * 4 + cc + 1]};
#pragma unroll
        for (int d = 0; d < 3; d++)
          rel2[n][d] = (f32x2){cr[r * 4 + cc][d] - cr[5][d],
                               cr[r * 4 + cc + 1][d] - cr[6][d]};
      }
  }

  f32x2 eA = {0.f, 0.f}, eB = {0.f, 0.f}, eC = {0.f, 0.f};
  u16* o16 = (u16*)out;
  float* of = (float*)out;
  const f32x2 zero2 = {0.f, 0.f};
  const u32* lt32 = (const u32*)ltile;       // row stride 256 u32
  int tm = max(tid - 1, 0), tp = min(tid + 1, 255);  // clamped (edge cols masked)

#pragma unroll 4
  for (int j = 0; j < 16; j++) {
    int o = grp * 16 + j;
    u32 tw[3][3];
#pragma unroll
    for (int r = 0; r < 3; r++) {
      int rb = (j * 3 + r) << 8;
      tw[r][0] = lt32[rb + tm];
      tw[r][1] = lt32[rb + tid];
      tw[r][2] = lt32[rb + tp];
    }
    float Pxs = sP[j][0], Pys = sP[j][1], Pzs = sP[j][2], Pws = sP[j][3];
    f32x2 Px = {Pxs, Pxs}, Py = {Pys, Pys}, Pz = {Pzs, Pzs}, Pw = {Pws, Pws};
    f32x2 g = {0.f, 0.f};
#pragma unroll
    for (int r = 0; r < 3; r++) {
      float tm1 = bfhi(tw[r][0]);   // col w-1
      float t0  = bflo(tw[r][1]);   // col w
      float tp1 = bfhi(tw[r][1]);   // col w+1
      float tp2 = bflo(tw[r][2]);   // col w+2
      f32x2 tv[3] = {{tm1, t0}, {t0, tp1}, {tp1, tp2}};
#pragma unroll
      for (int cc = 0; cc < 3; cc++) {
        int n = r * 3 + cc;
        f32x2 pos = pk_max(pk_fma(Px, rel2[n][0],
                           pk_fma(Py, rel2[n][1],
                           pk_fma(Pz, rel2[n][2], Pw))), zero2);
        g = pk_max(g, (tv[cc] + pos) * mv2[n]);
      }
    }
    int gi = (b * 128 + o) * HW + hw;
    if (isbf) *(u32*)(o16 + gi) = (u32)f2bf(g.x) | ((u32)f2bf(g.y) << 16);
    else { of[gi] = g.x; of[gi + 1] = g.y; }
    f32x2 Ex = {sE[j][0], sE[j][0]}, Ey = {sE[j][1], sE[j][1]}, Ez = {sE[j][2], sE[j][2]};
    eA = pk_fma(Ex, g, eA);
    eB = pk_fma(Ey, g, eB);
    eC = pk_fma(Ez, g, eC);
  }
  *(f32x2*)(eap + (grp * 3 + 0) * NPX + px0) = eA;
  *(f32x2*)(eap + (grp * 3 + 1) * NPX + px0) = eB;
  *(f32x2*)(eap + (grp * 3 + 2) * NPX + px0) = eC;
}

// Final: sum 8 group partials, cart_out. 2 px/thread, grid 128.
__global__ __launch_bounds__(256) void final_kernel(const void* __restrict__ cart,
                                                    const void* __restrict__ rawmask,
                                                    const void* __restrict__ eg,
                                                    const void* __restrict__ eb,
                                                    const void* __restrict__ em,
                                                    const void* __restrict__ ev,
                                                    const void* __restrict__ fv,
                                                    const char* __restrict__ wsb,
                                                    void* __restrict__ out){
  const float* eap = (const float*)(wsb + EAP_OFF);
  bool isbf = sniff_bf16(fv);
  int enc = sniff_mask(rawmask);
  int px0 = (blockIdx.x * 256 + threadIdx.x) * 2;
  int b = px0 >> 15, hw = px0 & 32767;
  f32x2 s0 = {0.f, 0.f}, s1 = {0.f, 0.f}, s2 = {0.f, 0.f};
#pragma unroll
  for (int g = 0; g < 8; g++) {
    s0 += *(const f32x2*)(eap + (g * 3 + 0) * NPX + px0);
    s1 += *(const f32x2*)(eap + (g * 3 + 1) * NPX + px0);
    s2 += *(const f32x2*)(eap + (g * 3 + 2) * NPX + px0);
  }
  float she[3];
#pragma unroll
  for (int d = 0; d < 3; d++) {
    float se = ldp(eg, d, isbf) * __frsqrt_rn(ldp(ev, d, isbf) + EPS);
    she[d] = ldp(eb, d, isbf) - ldp(em, d, isbf) * se;
  }
  float m0 = mask_at(rawmask, b * HW + hw, enc);
  float m1 = mask_at(rawmask, b * HW + hw + 1, enc);
  float c0a, c0b, c1a, c1b, c2a, c2b;
  if (isbf) {
    const u16* cb = (const u16*)cart + b * 3 * HW;
    c0a = bf2f(cb[hw]); c0b = bf2f(cb[hw + 1]);
    c1a = bf2f(cb[HW + hw]); c1b = bf2f(cb[HW + hw + 1]);
    c2a = bf2f(cb[2 * HW + hw]); c2b = bf2f(cb[2 * HW + hw + 1]);
  } else {
    const float* cb = (const float*)cart + b * 3 * HW;
    c0a = cb[hw]; c0b = cb[hw + 1];
    c1a = cb[HW + hw]; c1b = cb[HW + hw + 1];
    c2a = cb[2 * HW + hw]; c2b = cb[2 * HW + hw + 1];
  }
  float r0a = c0a + (s0.x + she[0]) * m0, r0b = c0b + (s0.y + she[0]) * m1;
  float r1a = c1a + (s1.x + she[1]) * m0, r1b = c1b + (s1.y + she[1]) * m1;
  float r2a = c2a + (s2.x + she[2]) * m0, r2b = c2b + (s2.y + she[2]) * m1;
  int cbase = GEO_SIZE + b * 3 * HW + hw;
  if (isbf) {
    u16* o16 = (u16*)out;
    *(u32*)(o16 + cbase)          = (u32)f2bf(r0a) | ((u32)f2bf(r0b) << 16);
    *(u32*)(o16 + cbase + HW)     = (u32)f2bf(r1a) | ((u32)f2bf(r1b) << 16);
    *(u32*)(o16 + cbase + 2 * HW) = (u32)f2bf(r2a) | ((u32)f2bf(r2b) << 16);
  } else {
    float* of = (float*)out;
    of[cbase] = r0a; of[cbase + 1] = r0b;
    of[cbase + HW] = r1a; of[cbase + HW + 1] = r1b;
    of[cbase + 2 * HW] = r2a; of[cbase + 2 * HW + 1] = r2b;
  }
}

extern "C" void kernel_launch(void* const* d_in, const int* in_sizes, int n_in,
                              void* d_out, int out_size, void* d_ws, size_t ws_size,
                              hipStream_t stream) {
  const void* feat = d_in[0];
  const void* cart = d_in[1];
  const void* mask = d_in[2];
  char* wsb = (char*)d_ws;

  hipLaunchKernelGGL(stage1_kernel, dim3(512), dim3(256), 0, stream,
                     feat, d_in[8], d_in[9], d_in[10], d_in[11], d_in[12], wsb);
  hipLaunchKernelGGL(stage2_kernel, dim3(1024), dim3(256), 0, stream,
                     cart, mask,
                     d_in[3], d_in[4], d_in[5], d_in[6], d_in[7],
                     d_in[13], d_in[14], d_in[15], d_in[16], d_in[17],
                     d_in[12], wsb, d_out);
  hipLaunchKernelGGL(final_kernel, dim3(128), dim3(256), 0, stream,
                     cart, mask, d_in[14], d_in[15], d_in[16], d_in[17],
                     d_in[12], wsb, d_out);
}